// Round 16
// baseline (79.495 us; speedup 1.0000x reference)
//
#include <hip/hip_runtime.h>
#include <math.h>
#include <stdint.h>

// GSA linear attention — bf16 MFMA. R15 base (78.96 us) + prologue overlap:
// k1/k4 issue their first LDS tiles BEFORE the wreg global loads so both
// latencies overlap (was: wreg -> VMCNT(0) drain -> issue -> wait, serial).
// k1: depth-2 prefetch, 4x16KB fixed buffers, W-in-regs, cvt_pk pack, no
// setprio in lockstep phase1. REGISTER RULE (R6/R8/R10/R13): k1 body needs
// ~128 live VGPRs; only __launch_bounds__(256,2) avoids spill (min>=3) and
// occupancy collapse (min=1).

typedef __attribute__((ext_vector_type(8))) short bf16x8;
typedef __attribute__((ext_vector_type(4))) float f32x4;

#define BATCH 8
#define CIN 256
#define NSP 4096
#define HEADS 8
#define DK 64
#define HID 512
#define OC 256
#define NCH 8   // k1 chunks of 512 n
#define NT 4    // 128-n tiles per chunk

#define VMCNT(n) asm volatile("s_waitcnt vmcnt(" #n ")" ::: "memory")
#define LGKM0()  asm volatile("s_waitcnt lgkmcnt(0)" ::: "memory")

__device__ __forceinline__ void barrier_fence() {
  asm volatile("" ::: "memory");
  __builtin_amdgcn_s_barrier();
  asm volatile("" ::: "memory");
}

__device__ __forceinline__ void gl16(const void* g, void* l) {
  __builtin_amdgcn_global_load_lds(
      (const __attribute__((address_space(1))) unsigned int*)g,
      (__attribute__((address_space(3))) unsigned int*)l, 16, 0, 0);
}

__device__ __forceinline__ short f2bf(float f) {
  union { float f; uint32_t u; } x; x.f = f;
  uint32_t r = x.u + 0x7fffu + ((x.u >> 16) & 1u);
  return (short)(r >> 16);
}

__device__ __forceinline__ unsigned cvt_pk_bf16(float lo, float hi) {
  unsigned r;
  asm("v_cvt_pk_bf16_f32 %0, %1, %2" : "=v"(r) : "v"(lo), "v"(hi));
  return r;
}

// ---------------- PREP (fused): imgT transpose (fat tiles) + wkv + wqT ----------------
// grid 800: [0,512) imgT 64c x 256n; [512,768) wkv; [768,800) wqT.
__global__ __launch_bounds__(256) void prep(
    const float* __restrict__ img, const float* __restrict__ w_qkv,
    short* __restrict__ imgT, short* __restrict__ wkv, short* __restrict__ wqT)
{
  __shared__ __align__(16) char smem[33024];
  const int bid = blockIdx.x;
  const int tid = threadIdx.x;
  if (bid < 512) {
    // img [b][c][n] f32 -> imgT [b][n][c] bf16, tile 64c x 256n
    unsigned (*t)[129] = (unsigned(*)[129])smem;   // packed 2xbf16 per uint
    const int b = bid >> 6, ct = (bid >> 4) & 3, nt = bid & 15;
    const float* src = img + ((size_t)b * CIN + ct * 64) * NSP + nt * 256;
#pragma unroll
    for (int k = 0; k < 16; ++k) {
      int i = tid + k * 256;            // 4096 float4s
      int c = i >> 6, f4 = i & 63;
      float4 v = *(const float4*)&src[(size_t)c * NSP + f4 * 4];
      t[c][f4 * 2]     = cvt_pk_bf16(v.x, v.y);
      t[c][f4 * 2 + 1] = cvt_pk_bf16(v.z, v.w);
    }
    __syncthreads();
    short* dst = imgT + ((size_t)b * NSP + nt * 256) * CIN + ct * 64;
#pragma unroll
    for (int k = 0; k < 8; ++k) {
      int j = tid + k * 256;            // 2048 stores of 16B
      int n = j >> 3, c8 = (j & 7) * 8;
      unsigned s[4];
#pragma unroll
      for (int q = 0; q < 4; ++q) {
        unsigned ua = t[c8 + 2 * q][n >> 1], ub = t[c8 + 2 * q + 1][n >> 1];
        unsigned ha = (n & 1) ? (ua >> 16) : (ua & 0xffffu);
        unsigned hb = (n & 1) ? (ub & 0xffff0000u) : (ub << 16);
        s[q] = ha | hb;
      }
      *(uint4*)&dst[(size_t)n * CIN + c8] = *(uint4*)s;
    }
  } else if (bid < 768) {
    // w_qkv k,v rows [512..1536) f32 -> bf16 [1024][256]
    int i = (bid - 512) * 256 + tid;
    const float* src = w_qkv + (size_t)HID * CIN;
    float4 v = ((const float4*)src)[i];
    unsigned s[2] = {cvt_pk_bf16(v.x, v.y), cvt_pk_bf16(v.z, v.w)};
    *(uint2*)(wkv + (size_t)i * 4) = *(uint2*)s;
  } else {
    // q rows [0..512) f32 -> WqT [256 c][512 hd] bf16
    float* tf = (float*)smem;   // [64][65]
    const int idx = bid - 768;
    const int hdt = idx & 7, ct = idx >> 3;
    for (int i = tid; i < 4096; i += 256) {
      int r = i >> 6, cc = i & 63;
      tf[r * 65 + cc] = w_qkv[(size_t)(hdt * 64 + r) * CIN + ct * 64 + cc];
    }
    __syncthreads();
#pragma unroll
    for (int k = 0; k < 4; ++k) {
      int j = tid + k * 256;
      int c = j >> 4, h4 = (j & 15) * 4;
      short r[4] = {f2bf(tf[(h4 + 0) * 65 + c]), f2bf(tf[(h4 + 1) * 65 + c]),
                    f2bf(tf[(h4 + 2) * 65 + c]), f2bf(tf[(h4 + 3) * 65 + c])};
      *(uint2*)&wqT[(size_t)(ct * 64 + c) * HID + hdt * 64 + h4] = *(uint2*)r;
    }
  }
}

// ---------------- K1: depth-2 prefetch kv-proj + exp + ctx ----------------
// grid 512 (xcd-grouped: 8 h per XCD share (b,ch) img tile). 256 thr = 4 waves.
// LDS 64K = 4x16K fixed buffers; phase2 scratch = B2+B3 overlay.
__global__ __launch_bounds__(256, 2) void k1_mfma(
    const short* __restrict__ imgT, const short* __restrict__ wkv,
    float* __restrict__ ctx_part, float* __restrict__ z_part)
{
  const int bi = blockIdx.x;
  const int x = bi & 7, m = bi >> 3;
  const int h = m & 7, g = (m >> 3) * 8 + x;   // g in [0,64)
  const int b = g >> 3, ch = g & 7;

  const int tid = threadIdx.x, w = tid >> 6, l = tid & 63;
  const int l15 = l & 15, l4 = l >> 4;

  __shared__ __align__(16) char sm[65536];
  char* B0 = sm;
  char* B1 = sm + 16384;
  char* B2 = sm + 32768;
  char* B3 = sm + 49152;
  char* scr = sm + 32768;   // phase2: ek [64 d][256B] | v [64 e][256B] at +16384

  const char* ibase = (const char*)imgT + (size_t)b * NSP * 512 + (size_t)ch * 512 * 512;
  const int rowpart = w * 8 + (l >> 3);
  const int colswz = ((l & 7) * 16) ^ (((l >> 3) & 7) << 4);

  auto issue_x = [&](char* buf, int t, int q) {
#pragma unroll
    for (int r = 0; r < 4; ++r) {
      int row = rowpart + r * 32;
      const char* src = ibase + (size_t)(t * 128 + row) * 512 + q * 128 + colswz;
      gl16(src, buf + (size_t)(w * 8 + r * 32) * 128);
    }
  };

  // prologue: issue first tiles FIRST so HBM latency overlaps the wreg loads
  issue_x(B0, 0, 0);
  issue_x(B1, 0, 1);

  // W in regs: wave w owns rows w*32..w*32+31 (w<2: k, w>=2: v)
  bf16x8 wreg[2][4][2];
#pragma unroll
  for (int tr = 0; tr < 2; ++tr) {
    int row = w * 32 + tr * 16 + l15;
    int gr = (row < 64) ? (h * 64 + row) : (512 + h * 64 + (row - 64));
    const char* base = (const char*)wkv + (size_t)gr * 512;
#pragma unroll
    for (int kq = 0; kq < 4; ++kq)
#pragma unroll
      for (int kk = 0; kk < 2; ++kk)
        wreg[tr][kq][kk] = *(const bf16x8*)(base + kq * 128 + kk * 64 + l4 * 16);
  }
  // no explicit drain: loop VMCNT(4) + compiler's wreg waits cover the mix

  f32x4 acc2[4];
#pragma unroll
  for (int i = 0; i < 4; ++i) acc2[i] = (f32x4){0.f, 0.f, 0.f, 0.f};
  float zacc[2][4];
#pragma unroll
  for (int i = 0; i < 2; ++i)
#pragma unroll
    for (int jj = 0; jj < 4; ++jj) zacc[i][jj] = 0.f;

#define P1Q(BUF, Q)                                                       \
  {                                                                       \
    _Pragma("unroll")                                                     \
    for (int kk = 0; kk < 2; ++kk) {                                      \
      bf16x8 bfr[8];                                                      \
      _Pragma("unroll")                                                   \
      for (int tn = 0; tn < 8; ++tn) {                                    \
        int n = tn * 16 + l15;                                            \
        bfr[tn] = *(bf16x8*)((BUF) + (size_t)n * 128 +                    \
                  ((kk * 64 + l4 * 16) ^ ((n & 7) << 4)));                \
      }                                                                   \
      _Pragma("unroll")                                                   \
      for (int tr = 0; tr < 2; ++tr)                                      \
        _Pragma("unroll")                                                 \
        for (int tn = 0; tn < 8; ++tn)                                    \
          acc1[tr][tn] = __builtin_amdgcn_mfma_f32_16x16x32_bf16(         \
              wreg[tr][Q][kk], bfr[tn], acc1[tr][tn], 0, 0, 0);           \
    }                                                                     \
  }

  for (int t = 0; t < NT; ++t) {
    const bool last = (t == NT - 1);
    f32x4 acc1[2][8];
#pragma unroll
    for (int i = 0; i < 2; ++i)
#pragma unroll
      for (int jj = 0; jj < 8; ++jj) acc1[i][jj] = (f32x4){0.f, 0.f, 0.f, 0.f};

    // step1: wait q0 (issued 2 phases ago); issue q2(t); compute q0
    VMCNT(4); barrier_fence();
    issue_x(B2, t, 2);
    P1Q(B0, 0);

    // step2: wait q1; issue q3(t); compute q1
    VMCNT(4); barrier_fence();
    issue_x(B3, t, 3);
    P1Q(B1, 1);

    // step3: wait q2; issue q0(t+1); compute q2
    VMCNT(4); barrier_fence();
    if (!last) issue_x(B0, t + 1, 0);
    P1Q(B2, 2);

    // step4: wait q3; issue q1(t+1); compute q3
    if (last) { VMCNT(0); } else { VMCNT(4); }
    barrier_fence();
    if (!last) issue_x(B1, t + 1, 1);
    P1Q(B3, 3);

    // step5: phase2 in B2+B3 (idle until next-tile steps 1/2 re-issue them)
    barrier_fence();   // all waves done reading B2/B3
    {
      char* dst = (w < 2) ? scr : (scr + 16384);
      const int rowb = (w & 1) * 32;
#pragma unroll
      for (int tr = 0; tr < 2; ++tr) {
#pragma unroll
        for (int tn = 0; tn < 8; ++tn) {
          f32x4 vv = acc1[tr][tn];
          float f0 = vv[0], f1 = vv[1], f2 = vv[2], f3 = vv[3];
          if (w < 2) {
            f0 = __expf(f0); f1 = __expf(f1); f2 = __expf(f2); f3 = __expf(f3);
            zacc[tr][0] += f0; zacc[tr][1] += f1;
            zacc[tr][2] += f2; zacc[tr][3] += f3;
          }
          unsigned p01 = cvt_pk_bf16(f0, f1);
          unsigned p23 = cvt_pk_bf16(f2, f3);
          unsigned q01 = (unsigned)__shfl_xor((int)p01, 1, 64);
          unsigned q23 = (unsigned)__shfl_xor((int)p23, 1, 64);
          int nl = tn * 16 + l15;
          int nb = 2 * (nl & ~1);
          int r0 = rowb + tr * 16 + l4 * 4;
          unsigned w0, w1; int rga, rgb;
          if (!(l15 & 1)) {
            w0 = (p01 & 0xffffu) | (q01 << 16);
            w1 = (p01 >> 16) | (q01 & 0xffff0000u);
            rga = 0; rgb = 1;
          } else {
            w0 = (q23 & 0xffffu) | (p23 << 16);
            w1 = (q23 >> 16) | (p23 & 0xffff0000u);
            rga = 2; rgb = 3;
          }
          int rowa = r0 + rga, rowbq = r0 + rgb;
          *(unsigned*)(dst + (size_t)rowa * 256 + (nb ^ ((rowa & 7) << 4))) = w0;
          *(unsigned*)(dst + (size_t)rowbq * 256 + (nb ^ ((rowbq & 7) << 4))) = w1;
        }
      }
    }
    LGKM0(); barrier_fence();
    // ctx MFMA: wave w = d-tile (16 d) x 4 e-tiles, K = 128 n
#pragma unroll
    for (int kk = 0; kk < 4; ++kk) {
      int dr = w * 16 + l15;
      bf16x8 a = *(bf16x8*)(scr + (size_t)dr * 256 + ((kk * 64 + l4 * 16) ^ ((dr & 7) << 4)));
      __builtin_amdgcn_s_setprio(1);
#pragma unroll
      for (int te = 0; te < 4; ++te) {
        int er = te * 16 + l15;
        bf16x8 bv = *(bf16x8*)(scr + 16384 + (size_t)er * 256 +
                               ((kk * 64 + l4 * 16) ^ ((er & 7) << 4)));
        acc2[te] = __builtin_amdgcn_mfma_f32_16x16x32_bf16(a, bv, acc2[te], 0, 0, 0);
      }
      __builtin_amdgcn_s_setprio(0);
    }
    // next-tile step1 barrier protects B2 from re-issue until ctx reads done
  }

  // ---- epilogue ----
  float* cp = ctx_part + ((size_t)(b * HEADS + h) * NCH + ch) * (DK * DK);
#pragma unroll
  for (int te = 0; te < 4; ++te) {
#pragma unroll
    for (int rg = 0; rg < 4; ++rg) {
      int d = w * 16 + l4 * 4 + rg;
      int e = te * 16 + l15;
      cp[d * 64 + e] = acc2[te][rg];
    }
  }
  if (w < 2) {
#pragma unroll
    for (int tr = 0; tr < 2; ++tr) {
#pragma unroll
      for (int rg = 0; rg < 4; ++rg) {
        float z = zacc[tr][rg];
        z += __shfl_xor(z, 1, 64); z += __shfl_xor(z, 2, 64);
        z += __shfl_xor(z, 4, 64); z += __shfl_xor(z, 8, 64);
        if (l15 == 0) {
          int d = w * 32 + tr * 16 + l4 * 4 + rg;
          z_part[((size_t)(b * HEADS + h) * NCH + ch) * DK + d] = z;
        }
      }
    }
  }
}

// ---------------- K23: reduce+normalize ctx, fold w_out -> M (bf16). grid 256 ----------------
__global__ __launch_bounds__(256) void k23_fold(
    const float* __restrict__ ctx_part, const float* __restrict__ z_part,
    const float* __restrict__ w_out, short* __restrict__ M)
{
  const int bid = blockIdx.x;
  const int h = bid & 7, b = (bid >> 3) & 7, ds = bid >> 6;
  const int bh = b * HEADS + h;
  const int d0 = ds * 16;
  __shared__ float cs[16][64];
  __shared__ float zs[16];

  {
    const int idx = threadIdx.x;
    const int dd = idx >> 4, e4 = (idx & 15) * 4;
    float4 s = {0.f, 0.f, 0.f, 0.f};
    for (int chh = 0; chh < NCH; ++chh) {
      const float* p = ctx_part + ((size_t)bh * NCH + chh) * 4096 + (d0 + dd) * 64 + e4;
      float4 v = *(const float4*)p;
      s.x += v.x; s.y += v.y; s.z += v.z; s.w += v.w;
    }
    if ((idx & 15) == 0) {
      float z = 0.f;
      for (int chh = 0; chh < NCH; ++chh)
        z += z_part[((size_t)bh * NCH + chh) * DK + d0 + dd];
      zs[dd] = z;
    }
    cs[dd][e4 + 0] = s.x; cs[dd][e4 + 1] = s.y;
    cs[dd][e4 + 2] = s.z; cs[dd][e4 + 3] = s.w;
  }
  __syncthreads();
  {
    const int idx = threadIdx.x;
    const int dd = idx >> 4, e4 = (idx & 15) * 4;
    float inv = 1.f / zs[dd];
    cs[dd][e4 + 0] *= inv; cs[dd][e4 + 1] *= inv;
    cs[dd][e4 + 2] *= inv; cs[dd][e4 + 3] *= inv;
  }
  __syncthreads();
  const int o = threadIdx.x;
  float4 wr[16];
#pragma unroll
  for (int q = 0; q < 16; ++q)
    wr[q] = *(const float4*)&w_out[(size_t)o * HID + h * DK + q * 4];
#pragma unroll
  for (int dd = 0; dd < 16; ++dd) {
    float a = 0.f;
#pragma unroll
    for (int q = 0; q < 16; ++q) {
      float4 w4 = wr[q];
      a += w4.x * cs[dd][q * 4 + 0] + w4.y * cs[dd][q * 4 + 1]
         + w4.z * cs[dd][q * 4 + 2] + w4.w * cs[dd][q * 4 + 3];
    }
    M[((size_t)b * OC + o) * HID + h * DK + d0 + dd] = f2bf(a);
  }
}

// ---------------- K3b: WM[b,o,c] = M[b,o,:] @ WqT[c,:]  (MFMA, double-buffered) ----------------
__global__ __launch_bounds__(512) void k3b_mfma(
    const short* __restrict__ M, const short* __restrict__ wqT,
    short* __restrict__ WM)
{
  const int ct = blockIdx.x, b = blockIdx.y;
  const int tid = threadIdx.x, w = tid >> 6, l = tid & 63;
  const int l15 = l & 15, l4 = l >> 4;

  __shared__ __align__(16) char sm3[81920];   // 2 x (At 32K + Bt 8K)

  f32x4 acc[4][2];
#pragma unroll
  for (int i = 0; i < 4; ++i)
#pragma unroll
    for (int jj = 0; jj < 2; ++jj) acc[i][jj] = (f32x4){0.f, 0.f, 0.f, 0.f};

  const int srow = tid >> 3, scol = (tid & 7) * 16;
  auto issue = [&](int st, int pb) {
    char* Ab = sm3 + pb * 40960;
    char* Bb = sm3 + 32768 + pb * 40960;
#pragma unroll
    for (int p = 0; p < 4; ++p) {
      int row = p * 64 + srow;
      const char* src = (const char*)M + ((size_t)b * OC + row) * 1024 + st * 128
                        + (scol ^ ((row & 7) << 4));
      gl16(src, Ab + (size_t)(p * 64 + w * 8) * 128);
    }
    {
      int row = srow;
      const char* src = (const char*)wqT + (size_t)(ct * 64 + row) * 1024 + st * 128
                        + (scol ^ ((row & 7) << 4));
      gl16(src, Bb + (size_t)(w * 8) * 128);
    }
  };

  issue(0, 0);
  for (int st = 0; st < 8; ++st) {
    const int pb = st & 1;
    if (st < 7) { issue(st + 1, pb ^ 1); VMCNT(5); } else { VMCNT(0); }
    barrier_fence();
    char* At = sm3 + pb * 40960;
    char* Bt = sm3 + 32768 + pb * 40960;
#pragma unroll
    for (int kk = 0; kk < 2; ++kk) {
      bf16x8 afr[4], bfr[2];
#pragma unroll
      for (int tr = 0; tr < 4; ++tr) {
        int o = (w >> 1) * 64 + tr * 16 + l15;
        afr[tr] = *(bf16x8*)(At + (size_t)o * 128 + ((kk * 64 + l4 * 16) ^ ((o & 7) << 4)));
      }
#pragma unroll
      for (int tn = 0; tn < 2; ++tn) {
        int c = (w & 1) * 32 + tn * 16 + l15;
        bfr[tn] = *(bf16x8*)(Bt + (size_t)c * 128 + ((kk * 64 + l4 * 16) ^ ((c & 7) << 4)));
      }
#pragma unroll
      for (int tr = 0; tr < 4; ++tr)
#pragma unroll
        for (int tn = 0; tn < 2; ++tn)
          acc[tr][tn] = __builtin_amdgcn_mfma_f32_16x16x32_bf16(afr[tr], bfr[tn], acc[tr][tn], 0, 0, 0);
    }
    barrier_fence();
  }
#pragma unroll
  for (int tr = 0; tr < 4; ++tr) {
#pragma unroll
    for (int tn = 0; tn < 2; ++tn) {
#pragma unroll
      for (int rg = 0; rg < 4; ++rg) {
        int o = (w >> 1) * 64 + tr * 16 + l4 * 4 + rg;
        int c = ct * 64 + (w & 1) * 32 + tn * 16 + l15;
        WM[((size_t)b * OC + o) * CIN + c] = f2bf(acc[tr][tn][rg]);
      }
    }
  }
}

// ---------------- K4: out = WM @ imgT^T + b_out (WM-in-regs, pipelined) ----------------
__global__ __launch_bounds__(512, 2) void k4_mfma(
    const short* __restrict__ WM, const short* __restrict__ imgT,
    const float* __restrict__ b_out, float* __restrict__ out)
{
  const int bi = blockIdx.x;
  const int b = bi & 7, nt = bi >> 3;
  const int n0 = nt * 64;
  const int tid = threadIdx.x, w = tid >> 6, l = tid & 63;
  const int l15 = l & 15, l4 = l >> 4;

  __shared__ __align__(16) char sm4[24576];
  char* B0 = sm4; char* B1 = sm4 + 8192; char* B2 = sm4 + 16384;

  const char* ibase = (const char*)imgT + ((size_t)b * NSP + n0) * 512;
  const int rowpart = w * 8 + (l >> 3);
  const int colswz = ((l & 7) * 16) ^ (((l >> 3) & 7) << 4);

  auto issue_x = [&](char* buf, int q) {
    const char* src = ibase + (size_t)rowpart * 512 + q * 128 + colswz;
    gl16(src, buf + (size_t)(w * 8) * 128);
  };

  // prologue: issue B0/B1 first, overlap with wreg loads, single drain
  issue_x(B0, 0);
  issue_x(B1, 1);

  bf16x8 wreg[2][4][2];
#pragma unroll
  for (int tr = 0; tr < 2; ++tr) {
    int o = w * 32 + tr * 16 + l15;
    const char* base = (const char*)WM + ((size_t)b * OC + o) * 512;
#pragma unroll
    for (int kq = 0; kq < 4; ++kq)
#pragma unroll
      for (int kk = 0; kk < 2; ++kk)
        wreg[tr][kq][kk] = *(const bf16x8*)(base + kq * 128 + kk * 64 + l4 * 16);
  }

  f32x4 acc[2][4];
#pragma unroll
  for (int i = 0; i < 2; ++i)
#pragma unroll
    for (int jj = 0; jj < 4; ++jj) acc[i][jj] = (f32x4){0.f, 0.f, 0.f, 0.f};

#define K4Q(BUF, Q)                                                       \
  {                                                                       \
    _Pragma("unroll")                                                     \
    for (int kk = 0; kk < 2; ++kk) {                                      \
      bf16x8 bfr[4];                                                      \
      _Pragma("unroll")                                                   \
      for (int tn = 0; tn < 4; ++tn) {                                    \
        int n = tn * 16 + l15;                                            \
        bfr[tn] = *(bf16x8*)((BUF) + (size_t)n * 128 +                    \
                  ((kk * 64 + l4 * 16) ^ ((n & 7) << 4)));                \
      }                                                                   \
      __builtin_amdgcn_s_setprio(1);                                      \
      _Pragma("unroll")                                                   \
      for (int tr = 0; tr < 2; ++tr)                                      \
        _Pragma("unroll")                                                 \
        for (int tn = 0; tn < 4; ++tn)                                    \
          acc[tr][tn] = __builtin_amdgcn_mfma_f32_16x16x32_bf16(          \
              wreg[tr][Q][kk], bfr[tn], acc[tr][tn], 0, 0, 0);            \
      __builtin_amdgcn_s_setprio(0);                                      \
    }                                                                     \
  }

  VMCNT(0); barrier_fence();        // B0,B1,wreg all landed (concurrent drain)
  issue_x(B2, 2);
  K4Q(B0, 0);

  barrier_fence();                  // all waves done reading B0
  issue_x(B0, 3);
  K4Q(B1, 1);

  VMCNT(1); barrier_fence();        // B2 landed (outstanding: B2, B0q3)
  K4Q(B2, 2);

  VMCNT(0); barrier_fence();        // B0q3 landed
  K4Q(B0, 3);

#pragma unroll
  for (int tr = 0; tr < 2; ++tr) {
#pragma unroll
    for (int rg = 0; rg < 4; ++rg) {
      int o = w * 32 + tr * 16 + l4 * 4 + rg;
      float bo = b_out[o];
#pragma unroll
      for (int tn = 0; tn < 4; ++tn) {
        int n = n0 + tn * 16 + l15;
        out[((size_t)b * OC + o) * NSP + n] = acc[tr][tn][rg] + bo;
      }
    }
  }
}

extern "C" void kernel_launch(void* const* d_in, const int* in_sizes, int n_in,
                              void* d_out, int out_size, void* d_ws, size_t ws_size,
                              hipStream_t stream) {
  (void)in_sizes; (void)n_in; (void)out_size; (void)ws_size;
  const float* img   = (const float*)d_in[0];
  const float* w_qkv = (const float*)d_in[1];
  const float* w_out = (const float*)d_in[2];
  const float* b_out = (const float*)d_in[3];
  float* out = (float*)d_out;

  char* ws = (char*)d_ws;
  short* imgT     = (short*)ws;                   // 16,777,216
  short* wkv      = (short*)(ws + 16777216);      //    524,288
  short* wqT      = (short*)(ws + 17301504);      //    262,144
  float* ctx_part = (float*)(ws + 17563648);      //  8,388,608 (64 bh x 8 ch x 4096)
  float* z_part   = (float*)(ws + 25952256);      //    131,072
  short* Mbuf     = (short*)(ws + 26083328);      //  2,097,152
  short* WMbuf    = (short*)(ws + 28180480);      //  1,048,576 (end ~29.2 MB)

  prep<<<dim3(800), 256, 0, stream>>>(img, w_qkv, imgT, wkv, wqT);
  k1_mfma<<<dim3(512), 256, 0, stream>>>(imgT, wkv, ctx_part, z_part);
  k23_fold<<<dim3(256), 256, 0, stream>>>(ctx_part, z_part, w_out, Mbuf);
  k3b_mfma<<<dim3(4, 8), 512, 0, stream>>>(Mbuf, wqT, WMbuf);
  k4_mfma<<<dim3(512), 512, 0, stream>>>(WMbuf, imgT, b_out, out);
}

// Round 17
// 79.127 us; speedup vs baseline: 1.0047x; 1.0047x over previous
//
#include <hip/hip_runtime.h>
#include <math.h>
#include <stdint.h>

// GSA linear attention — bf16 MFMA. R15 base (78.96 us, best) + k23 vectorized
// M-stores (16x2B scalar -> 2x uint4). k1: depth-2 prefetch, 4x16KB fixed
// buffers, W-in-regs, cvt_pk pack, no setprio in lockstep phase1.
// REGISTER RULE (R6/R8/R10/R13): k1 body needs ~128 live VGPRs; only
// __launch_bounds__(256,2) avoids spill (min>=3) and occupancy collapse (min=1).

typedef __attribute__((ext_vector_type(8))) short bf16x8;
typedef __attribute__((ext_vector_type(4))) float f32x4;

#define BATCH 8
#define CIN 256
#define NSP 4096
#define HEADS 8
#define DK 64
#define HID 512
#define OC 256
#define NCH 8   // k1 chunks of 512 n
#define NT 4    // 128-n tiles per chunk

#define VMCNT(n) asm volatile("s_waitcnt vmcnt(" #n ")" ::: "memory")
#define LGKM0()  asm volatile("s_waitcnt lgkmcnt(0)" ::: "memory")

__device__ __forceinline__ void barrier_fence() {
  asm volatile("" ::: "memory");
  __builtin_amdgcn_s_barrier();
  asm volatile("" ::: "memory");
}

__device__ __forceinline__ void gl16(const void* g, void* l) {
  __builtin_amdgcn_global_load_lds(
      (const __attribute__((address_space(1))) unsigned int*)g,
      (__attribute__((address_space(3))) unsigned int*)l, 16, 0, 0);
}

__device__ __forceinline__ short f2bf(float f) {
  union { float f; uint32_t u; } x; x.f = f;
  uint32_t r = x.u + 0x7fffu + ((x.u >> 16) & 1u);
  return (short)(r >> 16);
}

__device__ __forceinline__ unsigned cvt_pk_bf16(float lo, float hi) {
  unsigned r;
  asm("v_cvt_pk_bf16_f32 %0, %1, %2" : "=v"(r) : "v"(lo), "v"(hi));
  return r;
}

// ---------------- PREP (fused): imgT transpose (fat tiles) + wkv + wqT ----------------
// grid 800: [0,512) imgT 64c x 256n; [512,768) wkv; [768,800) wqT.
__global__ __launch_bounds__(256) void prep(
    const float* __restrict__ img, const float* __restrict__ w_qkv,
    short* __restrict__ imgT, short* __restrict__ wkv, short* __restrict__ wqT)
{
  __shared__ __align__(16) char smem[33024];
  const int bid = blockIdx.x;
  const int tid = threadIdx.x;
  if (bid < 512) {
    // img [b][c][n] f32 -> imgT [b][n][c] bf16, tile 64c x 256n
    unsigned (*t)[129] = (unsigned(*)[129])smem;   // packed 2xbf16 per uint
    const int b = bid >> 6, ct = (bid >> 4) & 3, nt = bid & 15;
    const float* src = img + ((size_t)b * CIN + ct * 64) * NSP + nt * 256;
#pragma unroll
    for (int k = 0; k < 16; ++k) {
      int i = tid + k * 256;            // 4096 float4s
      int c = i >> 6, f4 = i & 63;
      float4 v = *(const float4*)&src[(size_t)c * NSP + f4 * 4];
      t[c][f4 * 2]     = cvt_pk_bf16(v.x, v.y);
      t[c][f4 * 2 + 1] = cvt_pk_bf16(v.z, v.w);
    }
    __syncthreads();
    short* dst = imgT + ((size_t)b * NSP + nt * 256) * CIN + ct * 64;
#pragma unroll
    for (int k = 0; k < 8; ++k) {
      int j = tid + k * 256;            // 2048 stores of 16B
      int n = j >> 3, c8 = (j & 7) * 8;
      unsigned s[4];
#pragma unroll
      for (int q = 0; q < 4; ++q) {
        unsigned ua = t[c8 + 2 * q][n >> 1], ub = t[c8 + 2 * q + 1][n >> 1];
        unsigned ha = (n & 1) ? (ua >> 16) : (ua & 0xffffu);
        unsigned hb = (n & 1) ? (ub & 0xffff0000u) : (ub << 16);
        s[q] = ha | hb;
      }
      *(uint4*)&dst[(size_t)n * CIN + c8] = *(uint4*)s;
    }
  } else if (bid < 768) {
    // w_qkv k,v rows [512..1536) f32 -> bf16 [1024][256]
    int i = (bid - 512) * 256 + tid;
    const float* src = w_qkv + (size_t)HID * CIN;
    float4 v = ((const float4*)src)[i];
    unsigned s[2] = {cvt_pk_bf16(v.x, v.y), cvt_pk_bf16(v.z, v.w)};
    *(uint2*)(wkv + (size_t)i * 4) = *(uint2*)s;
  } else {
    // q rows [0..512) f32 -> WqT [256 c][512 hd] bf16
    float* tf = (float*)smem;   // [64][65]
    const int idx = bid - 768;
    const int hdt = idx & 7, ct = idx >> 3;
    for (int i = tid; i < 4096; i += 256) {
      int r = i >> 6, cc = i & 63;
      tf[r * 65 + cc] = w_qkv[(size_t)(hdt * 64 + r) * CIN + ct * 64 + cc];
    }
    __syncthreads();
#pragma unroll
    for (int k = 0; k < 4; ++k) {
      int j = tid + k * 256;
      int c = j >> 4, h4 = (j & 15) * 4;
      short r[4] = {f2bf(tf[(h4 + 0) * 65 + c]), f2bf(tf[(h4 + 1) * 65 + c]),
                    f2bf(tf[(h4 + 2) * 65 + c]), f2bf(tf[(h4 + 3) * 65 + c])};
      *(uint2*)&wqT[(size_t)(ct * 64 + c) * HID + hdt * 64 + h4] = *(uint2*)r;
    }
  }
}

// ---------------- K1: depth-2 prefetch kv-proj + exp + ctx ----------------
// grid 512 (xcd-grouped: 8 h per XCD share (b,ch) img tile). 256 thr = 4 waves.
// LDS 64K = 4x16K fixed buffers; phase2 scratch = B2+B3 overlay.
__global__ __launch_bounds__(256, 2) void k1_mfma(
    const short* __restrict__ imgT, const short* __restrict__ wkv,
    float* __restrict__ ctx_part, float* __restrict__ z_part)
{
  const int bi = blockIdx.x;
  const int x = bi & 7, m = bi >> 3;
  const int h = m & 7, g = (m >> 3) * 8 + x;   // g in [0,64)
  const int b = g >> 3, ch = g & 7;

  const int tid = threadIdx.x, w = tid >> 6, l = tid & 63;
  const int l15 = l & 15, l4 = l >> 4;

  __shared__ __align__(16) char sm[65536];
  char* B0 = sm;
  char* B1 = sm + 16384;
  char* B2 = sm + 32768;
  char* B3 = sm + 49152;
  char* scr = sm + 32768;   // phase2: ek [64 d][256B] | v [64 e][256B] at +16384

  // W in regs: wave w owns rows w*32..w*32+31 (w<2: k, w>=2: v)
  bf16x8 wreg[2][4][2];
#pragma unroll
  for (int tr = 0; tr < 2; ++tr) {
    int row = w * 32 + tr * 16 + l15;
    int gr = (row < 64) ? (h * 64 + row) : (512 + h * 64 + (row - 64));
    const char* base = (const char*)wkv + (size_t)gr * 512;
#pragma unroll
    for (int kq = 0; kq < 4; ++kq)
#pragma unroll
      for (int kk = 0; kk < 2; ++kk)
        wreg[tr][kq][kk] = *(const bf16x8*)(base + kq * 128 + kk * 64 + l4 * 16);
  }
  VMCNT(0);   // clean vmcnt before gl16 pipeline

  const char* ibase = (const char*)imgT + (size_t)b * NSP * 512 + (size_t)ch * 512 * 512;
  const int rowpart = w * 8 + (l >> 3);
  const int colswz = ((l & 7) * 16) ^ (((l >> 3) & 7) << 4);

  auto issue_x = [&](char* buf, int t, int q) {
#pragma unroll
    for (int r = 0; r < 4; ++r) {
      int row = rowpart + r * 32;
      const char* src = ibase + (size_t)(t * 128 + row) * 512 + q * 128 + colswz;
      gl16(src, buf + (size_t)(w * 8 + r * 32) * 128);
    }
  };

  issue_x(B0, 0, 0);
  issue_x(B1, 0, 1);

  f32x4 acc2[4];
#pragma unroll
  for (int i = 0; i < 4; ++i) acc2[i] = (f32x4){0.f, 0.f, 0.f, 0.f};
  float zacc[2][4];
#pragma unroll
  for (int i = 0; i < 2; ++i)
#pragma unroll
    for (int jj = 0; jj < 4; ++jj) zacc[i][jj] = 0.f;

#define P1Q(BUF, Q)                                                       \
  {                                                                       \
    _Pragma("unroll")                                                     \
    for (int kk = 0; kk < 2; ++kk) {                                      \
      bf16x8 bfr[8];                                                      \
      _Pragma("unroll")                                                   \
      for (int tn = 0; tn < 8; ++tn) {                                    \
        int n = tn * 16 + l15;                                            \
        bfr[tn] = *(bf16x8*)((BUF) + (size_t)n * 128 +                    \
                  ((kk * 64 + l4 * 16) ^ ((n & 7) << 4)));                \
      }                                                                   \
      _Pragma("unroll")                                                   \
      for (int tr = 0; tr < 2; ++tr)                                      \
        _Pragma("unroll")                                                 \
        for (int tn = 0; tn < 8; ++tn)                                    \
          acc1[tr][tn] = __builtin_amdgcn_mfma_f32_16x16x32_bf16(         \
              wreg[tr][Q][kk], bfr[tn], acc1[tr][tn], 0, 0, 0);           \
    }                                                                     \
  }

  for (int t = 0; t < NT; ++t) {
    const bool last = (t == NT - 1);
    f32x4 acc1[2][8];
#pragma unroll
    for (int i = 0; i < 2; ++i)
#pragma unroll
      for (int jj = 0; jj < 8; ++jj) acc1[i][jj] = (f32x4){0.f, 0.f, 0.f, 0.f};

    // step1: wait q0 (issued 2 phases ago); issue q2(t); compute q0
    VMCNT(4); barrier_fence();
    issue_x(B2, t, 2);
    P1Q(B0, 0);

    // step2: wait q1; issue q3(t); compute q1
    VMCNT(4); barrier_fence();
    issue_x(B3, t, 3);
    P1Q(B1, 1);

    // step3: wait q2; issue q0(t+1); compute q2
    VMCNT(4); barrier_fence();
    if (!last) issue_x(B0, t + 1, 0);
    P1Q(B2, 2);

    // step4: wait q3; issue q1(t+1); compute q3
    if (last) { VMCNT(0); } else { VMCNT(4); }
    barrier_fence();
    if (!last) issue_x(B1, t + 1, 1);
    P1Q(B3, 3);

    // step5: phase2 in B2+B3 (idle until next-tile steps 1/2 re-issue them)
    barrier_fence();   // all waves done reading B2/B3
    {
      char* dst = (w < 2) ? scr : (scr + 16384);
      const int rowb = (w & 1) * 32;
#pragma unroll
      for (int tr = 0; tr < 2; ++tr) {
#pragma unroll
        for (int tn = 0; tn < 8; ++tn) {
          f32x4 vv = acc1[tr][tn];
          float f0 = vv[0], f1 = vv[1], f2 = vv[2], f3 = vv[3];
          if (w < 2) {
            f0 = __expf(f0); f1 = __expf(f1); f2 = __expf(f2); f3 = __expf(f3);
            zacc[tr][0] += f0; zacc[tr][1] += f1;
            zacc[tr][2] += f2; zacc[tr][3] += f3;
          }
          unsigned p01 = cvt_pk_bf16(f0, f1);
          unsigned p23 = cvt_pk_bf16(f2, f3);
          unsigned q01 = (unsigned)__shfl_xor((int)p01, 1, 64);
          unsigned q23 = (unsigned)__shfl_xor((int)p23, 1, 64);
          int nl = tn * 16 + l15;
          int nb = 2 * (nl & ~1);
          int r0 = rowb + tr * 16 + l4 * 4;
          unsigned w0, w1; int rga, rgb;
          if (!(l15 & 1)) {
            w0 = (p01 & 0xffffu) | (q01 << 16);
            w1 = (p01 >> 16) | (q01 & 0xffff0000u);
            rga = 0; rgb = 1;
          } else {
            w0 = (q23 & 0xffffu) | (p23 << 16);
            w1 = (q23 >> 16) | (p23 & 0xffff0000u);
            rga = 2; rgb = 3;
          }
          int rowa = r0 + rga, rowbq = r0 + rgb;
          *(unsigned*)(dst + (size_t)rowa * 256 + (nb ^ ((rowa & 7) << 4))) = w0;
          *(unsigned*)(dst + (size_t)rowbq * 256 + (nb ^ ((rowbq & 7) << 4))) = w1;
        }
      }
    }
    LGKM0(); barrier_fence();
    // ctx MFMA: wave w = d-tile (16 d) x 4 e-tiles, K = 128 n
#pragma unroll
    for (int kk = 0; kk < 4; ++kk) {
      int dr = w * 16 + l15;
      bf16x8 a = *(bf16x8*)(scr + (size_t)dr * 256 + ((kk * 64 + l4 * 16) ^ ((dr & 7) << 4)));
      __builtin_amdgcn_s_setprio(1);
#pragma unroll
      for (int te = 0; te < 4; ++te) {
        int er = te * 16 + l15;
        bf16x8 bv = *(bf16x8*)(scr + 16384 + (size_t)er * 256 +
                               ((kk * 64 + l4 * 16) ^ ((er & 7) << 4)));
        acc2[te] = __builtin_amdgcn_mfma_f32_16x16x32_bf16(a, bv, acc2[te], 0, 0, 0);
      }
      __builtin_amdgcn_s_setprio(0);
    }
    // next-tile step1 barrier protects B2 from re-issue until ctx reads done
  }

  // ---- epilogue ----
  float* cp = ctx_part + ((size_t)(b * HEADS + h) * NCH + ch) * (DK * DK);
#pragma unroll
  for (int te = 0; te < 4; ++te) {
#pragma unroll
    for (int rg = 0; rg < 4; ++rg) {
      int d = w * 16 + l4 * 4 + rg;
      int e = te * 16 + l15;
      cp[d * 64 + e] = acc2[te][rg];
    }
  }
  if (w < 2) {
#pragma unroll
    for (int tr = 0; tr < 2; ++tr) {
#pragma unroll
      for (int rg = 0; rg < 4; ++rg) {
        float z = zacc[tr][rg];
        z += __shfl_xor(z, 1, 64); z += __shfl_xor(z, 2, 64);
        z += __shfl_xor(z, 4, 64); z += __shfl_xor(z, 8, 64);
        if (l15 == 0) {
          int d = w * 32 + tr * 16 + l4 * 4 + rg;
          z_part[((size_t)(b * HEADS + h) * NCH + ch) * DK + d] = z;
        }
      }
    }
  }
}

// ---------------- K23: reduce+normalize ctx, fold w_out -> M (bf16). grid 256 ----------------
__global__ __launch_bounds__(256) void k23_fold(
    const float* __restrict__ ctx_part, const float* __restrict__ z_part,
    const float* __restrict__ w_out, short* __restrict__ M)
{
  const int bid = blockIdx.x;
  const int h = bid & 7, b = (bid >> 3) & 7, ds = bid >> 6;
  const int bh = b * HEADS + h;
  const int d0 = ds * 16;
  __shared__ float cs[16][64];
  __shared__ float zs[16];

  {
    const int idx = threadIdx.x;
    const int dd = idx >> 4, e4 = (idx & 15) * 4;
    float4 s = {0.f, 0.f, 0.f, 0.f};
    for (int chh = 0; chh < NCH; ++chh) {
      const float* p = ctx_part + ((size_t)bh * NCH + chh) * 4096 + (d0 + dd) * 64 + e4;
      float4 v = *(const float4*)p;
      s.x += v.x; s.y += v.y; s.z += v.z; s.w += v.w;
    }
    if ((idx & 15) == 0) {
      float z = 0.f;
      for (int chh = 0; chh < NCH; ++chh)
        z += z_part[((size_t)bh * NCH + chh) * DK + d0 + dd];
      zs[dd] = z;
    }
    cs[dd][e4 + 0] = s.x; cs[dd][e4 + 1] = s.y;
    cs[dd][e4 + 2] = s.z; cs[dd][e4 + 3] = s.w;
  }
  __syncthreads();
  {
    const int idx = threadIdx.x;
    const int dd = idx >> 4, e4 = (idx & 15) * 4;
    float inv = 1.f / zs[dd];
    cs[dd][e4 + 0] *= inv; cs[dd][e4 + 1] *= inv;
    cs[dd][e4 + 2] *= inv; cs[dd][e4 + 3] *= inv;
  }
  __syncthreads();
  const int o = threadIdx.x;
  float4 wr[16];
#pragma unroll
  for (int q = 0; q < 16; ++q)
    wr[q] = *(const float4*)&w_out[(size_t)o * HID + h * DK + q * 4];
  unsigned mout[8];
#pragma unroll
  for (int dd = 0; dd < 16; dd += 2) {
    float a0 = 0.f, a1 = 0.f;
#pragma unroll
    for (int q = 0; q < 16; ++q) {
      float4 w4 = wr[q];
      a0 += w4.x * cs[dd][q * 4 + 0] + w4.y * cs[dd][q * 4 + 1]
          + w4.z * cs[dd][q * 4 + 2] + w4.w * cs[dd][q * 4 + 3];
      a1 += w4.x * cs[dd + 1][q * 4 + 0] + w4.y * cs[dd + 1][q * 4 + 1]
          + w4.z * cs[dd + 1][q * 4 + 2] + w4.w * cs[dd + 1][q * 4 + 3];
    }
    mout[dd >> 1] = cvt_pk_bf16(a0, a1);
  }
  short* mp = M + ((size_t)b * OC + o) * HID + h * DK + d0;
  *(uint4*)mp       = *(uint4*)&mout[0];
  *(uint4*)(mp + 8) = *(uint4*)&mout[4];
}

// ---------------- K3b: WM[b,o,c] = M[b,o,:] @ WqT[c,:]  (MFMA, double-buffered) ----------------
__global__ __launch_bounds__(512) void k3b_mfma(
    const short* __restrict__ M, const short* __restrict__ wqT,
    short* __restrict__ WM)
{
  const int ct = blockIdx.x, b = blockIdx.y;
  const int tid = threadIdx.x, w = tid >> 6, l = tid & 63;
  const int l15 = l & 15, l4 = l >> 4;

  __shared__ __align__(16) char sm3[81920];   // 2 x (At 32K + Bt 8K)

  f32x4 acc[4][2];
#pragma unroll
  for (int i = 0; i < 4; ++i)
#pragma unroll
    for (int jj = 0; jj < 2; ++jj) acc[i][jj] = (f32x4){0.f, 0.f, 0.f, 0.f};

  const int srow = tid >> 3, scol = (tid & 7) * 16;
  auto issue = [&](int st, int pb) {
    char* Ab = sm3 + pb * 40960;
    char* Bb = sm3 + 32768 + pb * 40960;
#pragma unroll
    for (int p = 0; p < 4; ++p) {
      int row = p * 64 + srow;
      const char* src = (const char*)M + ((size_t)b * OC + row) * 1024 + st * 128
                        + (scol ^ ((row & 7) << 4));
      gl16(src, Ab + (size_t)(p * 64 + w * 8) * 128);
    }
    {
      int row = srow;
      const char* src = (const char*)wqT + (size_t)(ct * 64 + row) * 1024 + st * 128
                        + (scol ^ ((row & 7) << 4));
      gl16(src, Bb + (size_t)(w * 8) * 128);
    }
  };

  issue(0, 0);
  for (int st = 0; st < 8; ++st) {
    const int pb = st & 1;
    if (st < 7) { issue(st + 1, pb ^ 1); VMCNT(5); } else { VMCNT(0); }
    barrier_fence();
    char* At = sm3 + pb * 40960;
    char* Bt = sm3 + 32768 + pb * 40960;
#pragma unroll
    for (int kk = 0; kk < 2; ++kk) {
      bf16x8 afr[4], bfr[2];
#pragma unroll
      for (int tr = 0; tr < 4; ++tr) {
        int o = (w >> 1) * 64 + tr * 16 + l15;
        afr[tr] = *(bf16x8*)(At + (size_t)o * 128 + ((kk * 64 + l4 * 16) ^ ((o & 7) << 4)));
      }
#pragma unroll
      for (int tn = 0; tn < 2; ++tn) {
        int c = (w & 1) * 32 + tn * 16 + l15;
        bfr[tn] = *(bf16x8*)(Bt + (size_t)c * 128 + ((kk * 64 + l4 * 16) ^ ((c & 7) << 4)));
      }
#pragma unroll
      for (int tr = 0; tr < 4; ++tr)
#pragma unroll
        for (int tn = 0; tn < 2; ++tn)
          acc[tr][tn] = __builtin_amdgcn_mfma_f32_16x16x32_bf16(afr[tr], bfr[tn], acc[tr][tn], 0, 0, 0);
    }
    barrier_fence();
  }
#pragma unroll
  for (int tr = 0; tr < 4; ++tr) {
#pragma unroll
    for (int tn = 0; tn < 2; ++tn) {
#pragma unroll
      for (int rg = 0; rg < 4; ++rg) {
        int o = (w >> 1) * 64 + tr * 16 + l4 * 4 + rg;
        int c = ct * 64 + (w & 1) * 32 + tn * 16 + l15;
        WM[((size_t)b * OC + o) * CIN + c] = f2bf(acc[tr][tn][rg]);
      }
    }
  }
}

// ---------------- K4: out = WM @ imgT^T + b_out (WM-in-regs, pipelined) ----------------
__global__ __launch_bounds__(512, 2) void k4_mfma(
    const short* __restrict__ WM, const short* __restrict__ imgT,
    const float* __restrict__ b_out, float* __restrict__ out)
{
  const int bi = blockIdx.x;
  const int b = bi & 7, nt = bi >> 3;
  const int n0 = nt * 64;
  const int tid = threadIdx.x, w = tid >> 6, l = tid & 63;
  const int l15 = l & 15, l4 = l >> 4;

  __shared__ __align__(16) char sm4[24576];
  char* B0 = sm4; char* B1 = sm4 + 8192; char* B2 = sm4 + 16384;

  bf16x8 wreg[2][4][2];
#pragma unroll
  for (int tr = 0; tr < 2; ++tr) {
    int o = w * 32 + tr * 16 + l15;
    const char* base = (const char*)WM + ((size_t)b * OC + o) * 512;
#pragma unroll
    for (int kq = 0; kq < 4; ++kq)
#pragma unroll
      for (int kk = 0; kk < 2; ++kk)
        wreg[tr][kq][kk] = *(const bf16x8*)(base + kq * 128 + kk * 64 + l4 * 16);
  }
  VMCNT(0);

  const char* ibase = (const char*)imgT + ((size_t)b * NSP + n0) * 512;
  const int rowpart = w * 8 + (l >> 3);
  const int colswz = ((l & 7) * 16) ^ (((l >> 3) & 7) << 4);

  auto issue_x = [&](char* buf, int q) {
    const char* src = ibase + (size_t)rowpart * 512 + q * 128 + colswz;
    gl16(src, buf + (size_t)(w * 8) * 128);
  };

  f32x4 acc[2][4];
#pragma unroll
  for (int i = 0; i < 2; ++i)
#pragma unroll
    for (int jj = 0; jj < 4; ++jj) acc[i][jj] = (f32x4){0.f, 0.f, 0.f, 0.f};

#define K4Q(BUF, Q)                                                       \
  {                                                                       \
    _Pragma("unroll")                                                     \
    for (int kk = 0; kk < 2; ++kk) {                                      \
      bf16x8 bfr[4];                                                      \
      _Pragma("unroll")                                                   \
      for (int tn = 0; tn < 4; ++tn) {                                    \
        int n = tn * 16 + l15;                                            \
        bfr[tn] = *(bf16x8*)((BUF) + (size_t)n * 128 +                    \
                  ((kk * 64 + l4 * 16) ^ ((n & 7) << 4)));                \
      }                                                                   \
      __builtin_amdgcn_s_setprio(1);                                      \
      _Pragma("unroll")                                                   \
      for (int tr = 0; tr < 2; ++tr)                                      \
        _Pragma("unroll")                                                 \
        for (int tn = 0; tn < 4; ++tn)                                    \
          acc[tr][tn] = __builtin_amdgcn_mfma_f32_16x16x32_bf16(          \
              wreg[tr][Q][kk], bfr[tn], acc[tr][tn], 0, 0, 0);            \
      __builtin_amdgcn_s_setprio(0);                                      \
    }                                                                     \
  }

  issue_x(B0, 0);
  issue_x(B1, 1);

  VMCNT(1); barrier_fence();
  issue_x(B2, 2);
  K4Q(B0, 0);

  VMCNT(1); barrier_fence();
  issue_x(B0, 3);
  K4Q(B1, 1);

  VMCNT(1); barrier_fence();
  K4Q(B2, 2);

  VMCNT(0); barrier_fence();
  K4Q(B0, 3);

#pragma unroll
  for (int tr = 0; tr < 2; ++tr) {
#pragma unroll
    for (int rg = 0; rg < 4; ++rg) {
      int o = w * 32 + tr * 16 + l4 * 4 + rg;
      float bo = b_out[o];
#pragma unroll
      for (int tn = 0; tn < 4; ++tn) {
        int n = n0 + tn * 16 + l15;
        out[((size_t)b * OC + o) * NSP + n] = acc[tr][tn][rg] + bo;
      }
    }
  }
}

extern "C" void kernel_launch(void* const* d_in, const int* in_sizes, int n_in,
                              void* d_out, int out_size, void* d_ws, size_t ws_size,
                              hipStream_t stream) {
  (void)in_sizes; (void)n_in; (void)out_size; (void)ws_size;
  const float* img   = (const float*)d_in[0];
  const float* w_qkv = (const float*)d_in[1];
  const float* w_out = (const float*)d_in[2];
  const float* b_out = (const float*)d_in[3];
  float* out = (float*)d_out;

  char* ws = (char*)d_ws;
  short* imgT     = (short*)ws;                   // 16,777,216
  short* wkv      = (short*)(ws + 16777216);      //    524,288
  short* wqT      = (short*)(ws + 17301504);      //    262,144
  float* ctx_part = (float*)(ws + 17563648);      //  8,388,608 (64 bh x 8 ch x 4096)
  float* z_part   = (float*)(ws + 25952256);      //    131,072
  short* Mbuf     = (short*)(ws + 26083328);      //  2,097,152
  short* WMbuf    = (short*)(ws + 28180480);      //  1,048,576 (end ~29.2 MB)

  prep<<<dim3(800), 256, 0, stream>>>(img, w_qkv, imgT, wkv, wqT);
  k1_mfma<<<dim3(512), 256, 0, stream>>>(imgT, wkv, ctx_part, z_part);
  k23_fold<<<dim3(256), 256, 0, stream>>>(ctx_part, z_part, w_out, Mbuf);
  k3b_mfma<<<dim3(4, 8), 512, 0, stream>>>(Mbuf, wqT, WMbuf);
  k4_mfma<<<dim3(512), 512, 0, stream>>>(WMbuf, imgT, b_out, out);
}

// Round 18
// 78.920 us; speedup vs baseline: 1.0073x; 1.0026x over previous
//
#include <hip/hip_runtime.h>
#include <math.h>
#include <stdint.h>

// GSA linear attention — bf16 MFMA. FINAL (R15 configuration, best measured:
// 78.96 us; 7.1x over fp32 baseline). Pipeline:
//   prep: img->imgT bf16 transpose (fat 64cx256n tiles, cvt_pk, uint4 stores)
//         + wkv bf16 + wqT transpose
//   k1:   kv-projection (W-in-regs, depth-2 prefetch over 4x16KB LDS buffers,
//         counted vmcnt) + exp(k) + ctx += ek@v^T (phase2 overlays B2/B3)
//   k23:  chunk-reduce + softmax-normalize ctx, fold w_out -> M (bf16)
//   k3b:  WM = M @ WqT^T (MFMA, double-buffered gl16)
//   k4:   out = WM @ imgT^T + b_out (WM-in-regs streaming MFMA)
// REGISTER RULE (R6/R8/R10/R13): k1 body needs ~128 live VGPRs; only
// __launch_bounds__(256,2) avoids spill (min>=3 squeezes to 84 VGPR ->
// ~100MB scratch traffic) and occupancy collapse (min=1 -> 144 VGPR, half occ).
// T5 note (R14): setprio removed from k1 lockstep phase1 (+2us), kept in
// phase2/k4 where wave roles diverge.

typedef __attribute__((ext_vector_type(8))) short bf16x8;
typedef __attribute__((ext_vector_type(4))) float f32x4;

#define BATCH 8
#define CIN 256
#define NSP 4096
#define HEADS 8
#define DK 64
#define HID 512
#define OC 256
#define NCH 8   // k1 chunks of 512 n
#define NT 4    // 128-n tiles per chunk

#define VMCNT(n) asm volatile("s_waitcnt vmcnt(" #n ")" ::: "memory")
#define LGKM0()  asm volatile("s_waitcnt lgkmcnt(0)" ::: "memory")

__device__ __forceinline__ void barrier_fence() {
  asm volatile("" ::: "memory");
  __builtin_amdgcn_s_barrier();
  asm volatile("" ::: "memory");
}

__device__ __forceinline__ void gl16(const void* g, void* l) {
  __builtin_amdgcn_global_load_lds(
      (const __attribute__((address_space(1))) unsigned int*)g,
      (__attribute__((address_space(3))) unsigned int*)l, 16, 0, 0);
}

__device__ __forceinline__ short f2bf(float f) {
  union { float f; uint32_t u; } x; x.f = f;
  uint32_t r = x.u + 0x7fffu + ((x.u >> 16) & 1u);
  return (short)(r >> 16);
}

__device__ __forceinline__ unsigned cvt_pk_bf16(float lo, float hi) {
  unsigned r;
  asm("v_cvt_pk_bf16_f32 %0, %1, %2" : "=v"(r) : "v"(lo), "v"(hi));
  return r;
}

// ---------------- PREP (fused): imgT transpose (fat tiles) + wkv + wqT ----------------
// grid 800: [0,512) imgT 64c x 256n; [512,768) wkv; [768,800) wqT.
__global__ __launch_bounds__(256) void prep(
    const float* __restrict__ img, const float* __restrict__ w_qkv,
    short* __restrict__ imgT, short* __restrict__ wkv, short* __restrict__ wqT)
{
  __shared__ __align__(16) char smem[33024];
  const int bid = blockIdx.x;
  const int tid = threadIdx.x;
  if (bid < 512) {
    // img [b][c][n] f32 -> imgT [b][n][c] bf16, tile 64c x 256n
    unsigned (*t)[129] = (unsigned(*)[129])smem;   // packed 2xbf16 per uint
    const int b = bid >> 6, ct = (bid >> 4) & 3, nt = bid & 15;
    const float* src = img + ((size_t)b * CIN + ct * 64) * NSP + nt * 256;
#pragma unroll
    for (int k = 0; k < 16; ++k) {
      int i = tid + k * 256;            // 4096 float4s
      int c = i >> 6, f4 = i & 63;
      float4 v = *(const float4*)&src[(size_t)c * NSP + f4 * 4];
      t[c][f4 * 2]     = cvt_pk_bf16(v.x, v.y);
      t[c][f4 * 2 + 1] = cvt_pk_bf16(v.z, v.w);
    }
    __syncthreads();
    short* dst = imgT + ((size_t)b * NSP + nt * 256) * CIN + ct * 64;
#pragma unroll
    for (int k = 0; k < 8; ++k) {
      int j = tid + k * 256;            // 2048 stores of 16B
      int n = j >> 3, c8 = (j & 7) * 8;
      unsigned s[4];
#pragma unroll
      for (int q = 0; q < 4; ++q) {
        unsigned ua = t[c8 + 2 * q][n >> 1], ub = t[c8 + 2 * q + 1][n >> 1];
        unsigned ha = (n & 1) ? (ua >> 16) : (ua & 0xffffu);
        unsigned hb = (n & 1) ? (ub & 0xffff0000u) : (ub << 16);
        s[q] = ha | hb;
      }
      *(uint4*)&dst[(size_t)n * CIN + c8] = *(uint4*)s;
    }
  } else if (bid < 768) {
    // w_qkv k,v rows [512..1536) f32 -> bf16 [1024][256]
    int i = (bid - 512) * 256 + tid;
    const float* src = w_qkv + (size_t)HID * CIN;
    float4 v = ((const float4*)src)[i];
    unsigned s[2] = {cvt_pk_bf16(v.x, v.y), cvt_pk_bf16(v.z, v.w)};
    *(uint2*)(wkv + (size_t)i * 4) = *(uint2*)s;
  } else {
    // q rows [0..512) f32 -> WqT [256 c][512 hd] bf16
    float* tf = (float*)smem;   // [64][65]
    const int idx = bid - 768;
    const int hdt = idx & 7, ct = idx >> 3;
    for (int i = tid; i < 4096; i += 256) {
      int r = i >> 6, cc = i & 63;
      tf[r * 65 + cc] = w_qkv[(size_t)(hdt * 64 + r) * CIN + ct * 64 + cc];
    }
    __syncthreads();
#pragma unroll
    for (int k = 0; k < 4; ++k) {
      int j = tid + k * 256;
      int c = j >> 4, h4 = (j & 15) * 4;
      short r[4] = {f2bf(tf[(h4 + 0) * 65 + c]), f2bf(tf[(h4 + 1) * 65 + c]),
                    f2bf(tf[(h4 + 2) * 65 + c]), f2bf(tf[(h4 + 3) * 65 + c])};
      *(uint2*)&wqT[(size_t)(ct * 64 + c) * HID + hdt * 64 + h4] = *(uint2*)r;
    }
  }
}

// ---------------- K1: depth-2 prefetch kv-proj + exp + ctx ----------------
// grid 512 (xcd-grouped: 8 h per XCD share (b,ch) img tile). 256 thr = 4 waves.
// LDS 64K = 4x16K fixed buffers; phase2 scratch = B2+B3 overlay.
__global__ __launch_bounds__(256, 2) void k1_mfma(
    const short* __restrict__ imgT, const short* __restrict__ wkv,
    float* __restrict__ ctx_part, float* __restrict__ z_part)
{
  const int bi = blockIdx.x;
  const int x = bi & 7, m = bi >> 3;
  const int h = m & 7, g = (m >> 3) * 8 + x;   // g in [0,64)
  const int b = g >> 3, ch = g & 7;

  const int tid = threadIdx.x, w = tid >> 6, l = tid & 63;
  const int l15 = l & 15, l4 = l >> 4;

  __shared__ __align__(16) char sm[65536];
  char* B0 = sm;
  char* B1 = sm + 16384;
  char* B2 = sm + 32768;
  char* B3 = sm + 49152;
  char* scr = sm + 32768;   // phase2: ek [64 d][256B] | v [64 e][256B] at +16384

  // W in regs: wave w owns rows w*32..w*32+31 (w<2: k, w>=2: v)
  bf16x8 wreg[2][4][2];
#pragma unroll
  for (int tr = 0; tr < 2; ++tr) {
    int row = w * 32 + tr * 16 + l15;
    int gr = (row < 64) ? (h * 64 + row) : (512 + h * 64 + (row - 64));
    const char* base = (const char*)wkv + (size_t)gr * 512;
#pragma unroll
    for (int kq = 0; kq < 4; ++kq)
#pragma unroll
      for (int kk = 0; kk < 2; ++kk)
        wreg[tr][kq][kk] = *(const bf16x8*)(base + kq * 128 + kk * 64 + l4 * 16);
  }
  VMCNT(0);   // clean vmcnt before gl16 pipeline

  const char* ibase = (const char*)imgT + (size_t)b * NSP * 512 + (size_t)ch * 512 * 512;
  const int rowpart = w * 8 + (l >> 3);
  const int colswz = ((l & 7) * 16) ^ (((l >> 3) & 7) << 4);

  auto issue_x = [&](char* buf, int t, int q) {
#pragma unroll
    for (int r = 0; r < 4; ++r) {
      int row = rowpart + r * 32;
      const char* src = ibase + (size_t)(t * 128 + row) * 512 + q * 128 + colswz;
      gl16(src, buf + (size_t)(w * 8 + r * 32) * 128);
    }
  };

  issue_x(B0, 0, 0);
  issue_x(B1, 0, 1);

  f32x4 acc2[4];
#pragma unroll
  for (int i = 0; i < 4; ++i) acc2[i] = (f32x4){0.f, 0.f, 0.f, 0.f};
  float zacc[2][4];
#pragma unroll
  for (int i = 0; i < 2; ++i)
#pragma unroll
    for (int jj = 0; jj < 4; ++jj) zacc[i][jj] = 0.f;

#define P1Q(BUF, Q)                                                       \
  {                                                                       \
    _Pragma("unroll")                                                     \
    for (int kk = 0; kk < 2; ++kk) {                                      \
      bf16x8 bfr[8];                                                      \
      _Pragma("unroll")                                                   \
      for (int tn = 0; tn < 8; ++tn) {                                    \
        int n = tn * 16 + l15;                                            \
        bfr[tn] = *(bf16x8*)((BUF) + (size_t)n * 128 +                    \
                  ((kk * 64 + l4 * 16) ^ ((n & 7) << 4)));                \
      }                                                                   \
      _Pragma("unroll")                                                   \
      for (int tr = 0; tr < 2; ++tr)                                      \
        _Pragma("unroll")                                                 \
        for (int tn = 0; tn < 8; ++tn)                                    \
          acc1[tr][tn] = __builtin_amdgcn_mfma_f32_16x16x32_bf16(         \
              wreg[tr][Q][kk], bfr[tn], acc1[tr][tn], 0, 0, 0);           \
    }                                                                     \
  }

  for (int t = 0; t < NT; ++t) {
    const bool last = (t == NT - 1);
    f32x4 acc1[2][8];
#pragma unroll
    for (int i = 0; i < 2; ++i)
#pragma unroll
      for (int jj = 0; jj < 8; ++jj) acc1[i][jj] = (f32x4){0.f, 0.f, 0.f, 0.f};

    // step1: wait q0 (issued 2 phases ago); issue q2(t); compute q0
    VMCNT(4); barrier_fence();
    issue_x(B2, t, 2);
    P1Q(B0, 0);

    // step2: wait q1; issue q3(t); compute q1
    VMCNT(4); barrier_fence();
    issue_x(B3, t, 3);
    P1Q(B1, 1);

    // step3: wait q2; issue q0(t+1); compute q2
    VMCNT(4); barrier_fence();
    if (!last) issue_x(B0, t + 1, 0);
    P1Q(B2, 2);

    // step4: wait q3; issue q1(t+1); compute q3
    if (last) { VMCNT(0); } else { VMCNT(4); }
    barrier_fence();
    if (!last) issue_x(B1, t + 1, 1);
    P1Q(B3, 3);

    // step5: phase2 in B2+B3 (idle until next-tile steps 1/2 re-issue them)
    barrier_fence();   // all waves done reading B2/B3
    {
      char* dst = (w < 2) ? scr : (scr + 16384);
      const int rowb = (w & 1) * 32;
#pragma unroll
      for (int tr = 0; tr < 2; ++tr) {
#pragma unroll
        for (int tn = 0; tn < 8; ++tn) {
          f32x4 vv = acc1[tr][tn];
          float f0 = vv[0], f1 = vv[1], f2 = vv[2], f3 = vv[3];
          if (w < 2) {
            f0 = __expf(f0); f1 = __expf(f1); f2 = __expf(f2); f3 = __expf(f3);
            zacc[tr][0] += f0; zacc[tr][1] += f1;
            zacc[tr][2] += f2; zacc[tr][3] += f3;
          }
          unsigned p01 = cvt_pk_bf16(f0, f1);
          unsigned p23 = cvt_pk_bf16(f2, f3);
          unsigned q01 = (unsigned)__shfl_xor((int)p01, 1, 64);
          unsigned q23 = (unsigned)__shfl_xor((int)p23, 1, 64);
          int nl = tn * 16 + l15;
          int nb = 2 * (nl & ~1);
          int r0 = rowb + tr * 16 + l4 * 4;
          unsigned w0, w1; int rga, rgb;
          if (!(l15 & 1)) {
            w0 = (p01 & 0xffffu) | (q01 << 16);
            w1 = (p01 >> 16) | (q01 & 0xffff0000u);
            rga = 0; rgb = 1;
          } else {
            w0 = (q23 & 0xffffu) | (p23 << 16);
            w1 = (q23 >> 16) | (p23 & 0xffff0000u);
            rga = 2; rgb = 3;
          }
          int rowa = r0 + rga, rowbq = r0 + rgb;
          *(unsigned*)(dst + (size_t)rowa * 256 + (nb ^ ((rowa & 7) << 4))) = w0;
          *(unsigned*)(dst + (size_t)rowbq * 256 + (nb ^ ((rowbq & 7) << 4))) = w1;
        }
      }
    }
    LGKM0(); barrier_fence();
    // ctx MFMA: wave w = d-tile (16 d) x 4 e-tiles, K = 128 n
#pragma unroll
    for (int kk = 0; kk < 4; ++kk) {
      int dr = w * 16 + l15;
      bf16x8 a = *(bf16x8*)(scr + (size_t)dr * 256 + ((kk * 64 + l4 * 16) ^ ((dr & 7) << 4)));
      __builtin_amdgcn_s_setprio(1);
#pragma unroll
      for (int te = 0; te < 4; ++te) {
        int er = te * 16 + l15;
        bf16x8 bv = *(bf16x8*)(scr + 16384 + (size_t)er * 256 +
                               ((kk * 64 + l4 * 16) ^ ((er & 7) << 4)));
        acc2[te] = __builtin_amdgcn_mfma_f32_16x16x32_bf16(a, bv, acc2[te], 0, 0, 0);
      }
      __builtin_amdgcn_s_setprio(0);
    }
    // next-tile step1 barrier protects B2 from re-issue until ctx reads done
  }

  // ---- epilogue ----
  float* cp = ctx_part + ((size_t)(b * HEADS + h) * NCH + ch) * (DK * DK);
#pragma unroll
  for (int te = 0; te < 4; ++te) {
#pragma unroll
    for (int rg = 0; rg < 4; ++rg) {
      int d = w * 16 + l4 * 4 + rg;
      int e = te * 16 + l15;
      cp[d * 64 + e] = acc2[te][rg];
    }
  }
  if (w < 2) {
#pragma unroll
    for (int tr = 0; tr < 2; ++tr) {
#pragma unroll
      for (int rg = 0; rg < 4; ++rg) {
        float z = zacc[tr][rg];
        z += __shfl_xor(z, 1, 64); z += __shfl_xor(z, 2, 64);
        z += __shfl_xor(z, 4, 64); z += __shfl_xor(z, 8, 64);
        if (l15 == 0) {
          int d = w * 32 + tr * 16 + l4 * 4 + rg;
          z_part[((size_t)(b * HEADS + h) * NCH + ch) * DK + d] = z;
        }
      }
    }
  }
}

// ---------------- K23: reduce+normalize ctx, fold w_out -> M (bf16). grid 256 ----------------
__global__ __launch_bounds__(256) void k23_fold(
    const float* __restrict__ ctx_part, const float* __restrict__ z_part,
    const float* __restrict__ w_out, short* __restrict__ M)
{
  const int bid = blockIdx.x;
  const int h = bid & 7, b = (bid >> 3) & 7, ds = bid >> 6;
  const int bh = b * HEADS + h;
  const int d0 = ds * 16;
  __shared__ float cs[16][64];
  __shared__ float zs[16];

  {
    const int idx = threadIdx.x;
    const int dd = idx >> 4, e4 = (idx & 15) * 4;
    float4 s = {0.f, 0.f, 0.f, 0.f};
    for (int chh = 0; chh < NCH; ++chh) {
      const float* p = ctx_part + ((size_t)bh * NCH + chh) * 4096 + (d0 + dd) * 64 + e4;
      float4 v = *(const float4*)p;
      s.x += v.x; s.y += v.y; s.z += v.z; s.w += v.w;
    }
    if ((idx & 15) == 0) {
      float z = 0.f;
      for (int chh = 0; chh < NCH; ++chh)
        z += z_part[((size_t)bh * NCH + chh) * DK + d0 + dd];
      zs[dd] = z;
    }
    cs[dd][e4 + 0] = s.x; cs[dd][e4 + 1] = s.y;
    cs[dd][e4 + 2] = s.z; cs[dd][e4 + 3] = s.w;
  }
  __syncthreads();
  {
    const int idx = threadIdx.x;
    const int dd = idx >> 4, e4 = (idx & 15) * 4;
    float inv = 1.f / zs[dd];
    cs[dd][e4 + 0] *= inv; cs[dd][e4 + 1] *= inv;
    cs[dd][e4 + 2] *= inv; cs[dd][e4 + 3] *= inv;
  }
  __syncthreads();
  const int o = threadIdx.x;
  float4 wr[16];
#pragma unroll
  for (int q = 0; q < 16; ++q)
    wr[q] = *(const float4*)&w_out[(size_t)o * HID + h * DK + q * 4];
#pragma unroll
  for (int dd = 0; dd < 16; ++dd) {
    float a = 0.f;
#pragma unroll
    for (int q = 0; q < 16; ++q) {
      float4 w4 = wr[q];
      a += w4.x * cs[dd][q * 4 + 0] + w4.y * cs[dd][q * 4 + 1]
         + w4.z * cs[dd][q * 4 + 2] + w4.w * cs[dd][q * 4 + 3];
    }
    M[((size_t)b * OC + o) * HID + h * DK + d0 + dd] = f2bf(a);
  }
}

// ---------------- K3b: WM[b,o,c] = M[b,o,:] @ WqT[c,:]  (MFMA, double-buffered) ----------------
__global__ __launch_bounds__(512) void k3b_mfma(
    const short* __restrict__ M, const short* __restrict__ wqT,
    short* __restrict__ WM)
{
  const int ct = blockIdx.x, b = blockIdx.y;
  const int tid = threadIdx.x, w = tid >> 6, l = tid & 63;
  const int l15 = l & 15, l4 = l >> 4;

  __shared__ __align__(16) char sm3[81920];   // 2 x (At 32K + Bt 8K)

  f32x4 acc[4][2];
#pragma unroll
  for (int i = 0; i < 4; ++i)
#pragma unroll
    for (int jj = 0; jj < 2; ++jj) acc[i][jj] = (f32x4){0.f, 0.f, 0.f, 0.f};

  const int srow = tid >> 3, scol = (tid & 7) * 16;
  auto issue = [&](int st, int pb) {
    char* Ab = sm3 + pb * 40960;
    char* Bb = sm3 + 32768 + pb * 40960;
#pragma unroll
    for (int p = 0; p < 4; ++p) {
      int row = p * 64 + srow;
      const char* src = (const char*)M + ((size_t)b * OC + row) * 1024 + st * 128
                        + (scol ^ ((row & 7) << 4));
      gl16(src, Ab + (size_t)(p * 64 + w * 8) * 128);
    }
    {
      int row = srow;
      const char* src = (const char*)wqT + (size_t)(ct * 64 + row) * 1024 + st * 128
                        + (scol ^ ((row & 7) << 4));
      gl16(src, Bb + (size_t)(w * 8) * 128);
    }
  };

  issue(0, 0);
  for (int st = 0; st < 8; ++st) {
    const int pb = st & 1;
    if (st < 7) { issue(st + 1, pb ^ 1); VMCNT(5); } else { VMCNT(0); }
    barrier_fence();
    char* At = sm3 + pb * 40960;
    char* Bt = sm3 + 32768 + pb * 40960;
#pragma unroll
    for (int kk = 0; kk < 2; ++kk) {
      bf16x8 afr[4], bfr[2];
#pragma unroll
      for (int tr = 0; tr < 4; ++tr) {
        int o = (w >> 1) * 64 + tr * 16 + l15;
        afr[tr] = *(bf16x8*)(At + (size_t)o * 128 + ((kk * 64 + l4 * 16) ^ ((o & 7) << 4)));
      }
#pragma unroll
      for (int tn = 0; tn < 2; ++tn) {
        int c = (w & 1) * 32 + tn * 16 + l15;
        bfr[tn] = *(bf16x8*)(Bt + (size_t)c * 128 + ((kk * 64 + l4 * 16) ^ ((c & 7) << 4)));
      }
#pragma unroll
      for (int tr = 0; tr < 4; ++tr)
#pragma unroll
        for (int tn = 0; tn < 2; ++tn)
          acc[tr][tn] = __builtin_amdgcn_mfma_f32_16x16x32_bf16(afr[tr], bfr[tn], acc[tr][tn], 0, 0, 0);
    }
    barrier_fence();
  }
#pragma unroll
  for (int tr = 0; tr < 4; ++tr) {
#pragma unroll
    for (int tn = 0; tn < 2; ++tn) {
#pragma unroll
      for (int rg = 0; rg < 4; ++rg) {
        int o = (w >> 1) * 64 + tr * 16 + l4 * 4 + rg;
        int c = ct * 64 + (w & 1) * 32 + tn * 16 + l15;
        WM[((size_t)b * OC + o) * CIN + c] = f2bf(acc[tr][tn][rg]);
      }
    }
  }
}

// ---------------- K4: out = WM @ imgT^T + b_out (WM-in-regs, pipelined) ----------------
__global__ __launch_bounds__(512, 2) void k4_mfma(
    const short* __restrict__ WM, const short* __restrict__ imgT,
    const float* __restrict__ b_out, float* __restrict__ out)
{
  const int bi = blockIdx.x;
  const int b = bi & 7, nt = bi >> 3;
  const int n0 = nt * 64;
  const int tid = threadIdx.x, w = tid >> 6, l = tid & 63;
  const int l15 = l & 15, l4 = l >> 4;

  __shared__ __align__(16) char sm4[24576];
  char* B0 = sm4; char* B1 = sm4 + 8192; char* B2 = sm4 + 16384;

  bf16x8 wreg[2][4][2];
#pragma unroll
  for (int tr = 0; tr < 2; ++tr) {
    int o = w * 32 + tr * 16 + l15;
    const char* base = (const char*)WM + ((size_t)b * OC + o) * 512;
#pragma unroll
    for (int kq = 0; kq < 4; ++kq)
#pragma unroll
      for (int kk = 0; kk < 2; ++kk)
        wreg[tr][kq][kk] = *(const bf16x8*)(base + kq * 128 + kk * 64 + l4 * 16);
  }
  VMCNT(0);

  const char* ibase = (const char*)imgT + ((size_t)b * NSP + n0) * 512;
  const int rowpart = w * 8 + (l >> 3);
  const int colswz = ((l & 7) * 16) ^ (((l >> 3) & 7) << 4);

  auto issue_x = [&](char* buf, int q) {
    const char* src = ibase + (size_t)rowpart * 512 + q * 128 + colswz;
    gl16(src, buf + (size_t)(w * 8) * 128);
  };

  f32x4 acc[2][4];
#pragma unroll
  for (int i = 0; i < 2; ++i)
#pragma unroll
    for (int jj = 0; jj < 4; ++jj) acc[i][jj] = (f32x4){0.f, 0.f, 0.f, 0.f};

#define K4Q(BUF, Q)                                                       \
  {                                                                       \
    _Pragma("unroll")                                                     \
    for (int kk = 0; kk < 2; ++kk) {                                      \
      bf16x8 bfr[4];                                                      \
      _Pragma("unroll")                                                   \
      for (int tn = 0; tn < 4; ++tn) {                                    \
        int n = tn * 16 + l15;                                            \
        bfr[tn] = *(bf16x8*)((BUF) + (size_t)n * 128 +                    \
                  ((kk * 64 + l4 * 16) ^ ((n & 7) << 4)));                \
      }                                                                   \
      __builtin_amdgcn_s_setprio(1);                                      \
      _Pragma("unroll")                                                   \
      for (int tr = 0; tr < 2; ++tr)                                      \
        _Pragma("unroll")                                                 \
        for (int tn = 0; tn < 4; ++tn)                                    \
          acc[tr][tn] = __builtin_amdgcn_mfma_f32_16x16x32_bf16(          \
              wreg[tr][Q][kk], bfr[tn], acc[tr][tn], 0, 0, 0);            \
      __builtin_amdgcn_s_setprio(0);                                      \
    }                                                                     \
  }

  issue_x(B0, 0);
  issue_x(B1, 1);

  VMCNT(1); barrier_fence();
  issue_x(B2, 2);
  K4Q(B0, 0);

  VMCNT(1); barrier_fence();
  issue_x(B0, 3);
  K4Q(B1, 1);

  VMCNT(1); barrier_fence();
  K4Q(B2, 2);

  VMCNT(0); barrier_fence();
  K4Q(B0, 3);

#pragma unroll
  for (int tr = 0; tr < 2; ++tr) {
#pragma unroll
    for (int rg = 0; rg < 4; ++rg) {
      int o = w * 32 + tr * 16 + l4 * 4 + rg;
      float bo = b_out[o];
#pragma unroll
      for (int tn = 0; tn < 4; ++tn) {
        int n = n0 + tn * 16 + l15;
        out[((size_t)b * OC + o) * NSP + n] = acc[tr][tn][rg] + bo;
      }
    }
  }
}

extern "C" void kernel_launch(void* const* d_in, const int* in_sizes, int n_in,
                              void* d_out, int out_size, void* d_ws, size_t ws_size,
                              hipStream_t stream) {
  (void)in_sizes; (void)n_in; (void)out_size; (void)ws_size;
  const float* img   = (const float*)d_in[0];
  const float* w_qkv = (const float*)d_in[1];
  const float* w_out = (const float*)d_in[2];
  const float* b_out = (const float*)d_in[3];
  float* out = (float*)d_out;

  char* ws = (char*)d_ws;
  short* imgT     = (short*)ws;                   // 16,777,216
  short* wkv      = (short*)(ws + 16777216);      //    524,288
  short* wqT      = (short*)(ws + 17301504);      //    262,144
  float* ctx_part = (float*)(ws + 17563648);      //  8,388,608 (64 bh x 8 ch x 4096)
  float* z_part   = (float*)(ws + 25952256);      //    131,072
  short* Mbuf     = (short*)(ws + 26083328);      //  2,097,152
  short* WMbuf    = (short*)(ws + 28180480);      //  1,048,576 (end ~29.2 MB)

  prep<<<dim3(800), 256, 0, stream>>>(img, w_qkv, imgT, wkv, wqT);
  k1_mfma<<<dim3(512), 256, 0, stream>>>(imgT, wkv, ctx_part, z_part);
  k23_fold<<<dim3(256), 256, 0, stream>>>(ctx_part, z_part, w_out, Mbuf);
  k3b_mfma<<<dim3(4, 8), 512, 0, stream>>>(Mbuf, wqT, WMbuf);
  k4_mfma<<<dim3(512), 512, 0, stream>>>(WMbuf, imgT, b_out, out);
}